// Round 1
// baseline (336.132 us; speedup 1.0000x reference)
//
#include <hip/hip_runtime.h>
#include <math.h>

#define NN 4096
#define FF 128
#define DD 64
#define HH 4
#define NC 256  // HH*DD output columns
#define NSPLIT 4

// ---------------------------------------------------------------------------
// Kernel A: h = features @ W[h]  (per head), plus a_self / a_neigh dots.
// grid (128, 4): x = 32-row n-tile, y = head. 256 threads.
// hfeat layout: [n][h*64+d]  (4096 x 256 fp32)
// aself/aneigh layout: [n*4 + h]
// ---------------------------------------------------------------------------
__global__ __launch_bounds__(256) void prep_kernel(
    const float* __restrict__ feats, const float* __restrict__ W,
    const float* __restrict__ ak, float* __restrict__ hfeat,
    float* __restrict__ aself, float* __restrict__ aneigh)
{
    __shared__ float Wt[64 * 132];   // W[h] transposed: [d][f], padded stride 132
    __shared__ float ft[32 * 128];   // features tile [r][f]
    const int t  = threadIdx.x;
    const int h  = blockIdx.y;
    const int n0 = blockIdx.x * 32;

    // stage W[h] (128x64 = 2048 float4), write transposed with pad
    {
        const float* Wh = W + h * (FF * DD);
        #pragma unroll
        for (int j = 0; j < 8; ++j) {
            int idx = j * 256 + t;        // float4 index 0..2047
            int f   = idx >> 4;           // 0..127
            int d4  = idx & 15;           // 16 float4 = 64 d
            float4 v = ((const float4*)Wh)[idx];
            Wt[(d4 * 4 + 0) * 132 + f] = v.x;
            Wt[(d4 * 4 + 1) * 132 + f] = v.y;
            Wt[(d4 * 4 + 2) * 132 + f] = v.z;
            Wt[(d4 * 4 + 3) * 132 + f] = v.w;
        }
        #pragma unroll
        for (int j = 0; j < 4; ++j) {
            int idx = j * 256 + t;        // float4 idx 0..1023
            int r = idx >> 5, f4 = idx & 31;
            ((float4*)ft)[r * 32 + f4] = ((const float4*)feats)[(size_t)(n0 + r) * 32 + f4];
        }
    }
    __syncthreads();

    const int d   = t & 63;
    const int wid = t >> 6;   // wave id 0..3 -> rows wid + 4*j
    float acc[8];
    #pragma unroll
    for (int j = 0; j < 8; ++j) acc[j] = 0.f;

    for (int f4 = 0; f4 < 32; ++f4) {
        const float4 w4 = *(const float4*)&Wt[d * 132 + f4 * 4];
        #pragma unroll
        for (int j = 0; j < 8; ++j) {
            const int r = wid + 4 * j;
            const float4 fv = *(const float4*)&ft[r * 128 + f4 * 4];
            acc[j] += fv.x * w4.x + fv.y * w4.y + fv.z * w4.z + fv.w * w4.w;
        }
    }

    const float aks = ak[h * 128 + d];
    const float akn = ak[h * 128 + 64 + d];
    #pragma unroll
    for (int j = 0; j < 8; ++j) {
        const int r = wid + 4 * j;
        const float hv = acc[j];
        hfeat[(size_t)(n0 + r) * NC + h * 64 + d] = hv;
        float v1 = hv * aks;
        float v2 = hv * akn;
        #pragma unroll
        for (int m = 32; m >= 1; m >>= 1) {
            v1 += __shfl_xor(v1, m, 64);
            v2 += __shfl_xor(v2, m, 64);
        }
        if (d == 0) {
            aself [(n0 + r) * 4 + h] = v1;
            aneigh[(n0 + r) * 4 + h] = v2;
        }
    }
}

// ---------------------------------------------------------------------------
// Kernel B: masked-softmax-weighted accumulation, split-K over m.
// grid (128, NSPLIT): x = 32-row n-tile, y = m-split (1024 m each). 256 thr.
// Per chunk of 32 m: compute w[h][ml][r] into LDS, stage hfeat chunk, then
// register-tiled fp32 GEMM: each thread does a 4-row x 8-col tile (one head).
// ---------------------------------------------------------------------------
__global__ __launch_bounds__(256) void attn_kernel(
    const int* __restrict__ adj, const float* __restrict__ hfeat,
    const float* __restrict__ aself, const float* __restrict__ aneigh,
    float* __restrict__ pacc, float* __restrict__ pden)
{
    __shared__ float w_lds[4 * 32 * 32];   // [h][ml][r]  16 KB
    __shared__ float hf_lds[32 * 256];     // [ml][c]     32 KB

    const int t    = threadIdx.x;
    const int n0   = blockIdx.x * 32;
    const int s    = blockIdx.y;

    const int rgrp = t >> 5;      // 0..7 -> rows rgrp*4 .. +3
    const int cgrp = t & 31;      // 0..31 -> cols cgrp*8 .. +7
    const int hh   = cgrp >> 3;   // head owning these 8 columns
    const int cb   = cgrp * 8;

    float acc[4][8];
    float den[4];
    #pragma unroll
    for (int i = 0; i < 4; ++i) {
        den[i] = 0.f;
        #pragma unroll
        for (int j = 0; j < 8; ++j) acc[i][j] = 0.f;
    }

    for (int chunk = 0; chunk < 32; ++chunk) {
        const int m0 = s * 1024 + chunk * 32;

        // ---- stage w: 4096 values, 16 per thread ----
        #pragma unroll
        for (int k = 0; k < 16; ++k) {
            int idx = k * 256 + t;
            int r   = idx & 31;
            int hw  = (idx >> 5) & 3;
            int ml  = idx >> 7;
            int a   = adj[(size_t)(n0 + r) * NN + m0 + ml];
            float sc = aself[(n0 + r) * 4 + hw] + aneigh[(m0 + ml) * 4 + hw];
            sc = sc >= 0.f ? sc : 0.2f * sc;
            float wv = a ? __expf(sc) : 0.f;
            w_lds[(hw * 32 + ml) * 32 + r] = wv;
        }
        // ---- stage hfeat chunk: 32 rows x 256 cols = 2048 float4 ----
        #pragma unroll
        for (int j = 0; j < 8; ++j) {
            int idx = j * 256 + t;
            int row = idx >> 6, c4 = idx & 63;
            ((float4*)hf_lds)[row * 64 + c4] =
                ((const float4*)hfeat)[(size_t)(m0 + row) * 64 + c4];
        }
        __syncthreads();

        // ---- register-tiled GEMM over the 32-m chunk ----
        #pragma unroll 4
        for (int mm = 0; mm < 32; ++mm) {
            const float4 w4 = *(const float4*)&w_lds[(hh * 32 + mm) * 32 + (rgrp << 2)];
            const float4 x  = *(const float4*)&hf_lds[mm * 256 + cb];
            const float4 y  = *(const float4*)&hf_lds[mm * 256 + cb + 4];
            const float wv[4] = {w4.x, w4.y, w4.z, w4.w};
            #pragma unroll
            for (int i = 0; i < 4; ++i) {
                acc[i][0] += wv[i] * x.x;
                acc[i][1] += wv[i] * x.y;
                acc[i][2] += wv[i] * x.z;
                acc[i][3] += wv[i] * x.w;
                acc[i][4] += wv[i] * y.x;
                acc[i][5] += wv[i] * y.y;
                acc[i][6] += wv[i] * y.z;
                acc[i][7] += wv[i] * y.w;
                den[i]    += wv[i];
            }
        }
        __syncthreads();
    }

    // ---- write partials ----
    #pragma unroll
    for (int i = 0; i < 4; ++i) {
        const int row = n0 + rgrp * 4 + i;
        float* p = &pacc[((size_t)(s * NN + row)) * NC + cb];
        float4 v0 = {acc[i][0], acc[i][1], acc[i][2], acc[i][3]};
        float4 v1 = {acc[i][4], acc[i][5], acc[i][6], acc[i][7]};
        ((float4*)p)[0] = v0;
        ((float4*)p)[1] = v1;
        if ((cgrp & 7) == 0) pden[(s * NN + row) * 4 + hh] = den[i];
    }
}

// ---------------------------------------------------------------------------
// Kernel C: reduce splits, divide by softmax denom, ReLU, write out.
// ---------------------------------------------------------------------------
__global__ __launch_bounds__(256) void finalize_kernel(
    const float* __restrict__ pacc, const float* __restrict__ pden,
    float* __restrict__ out)
{
    const int n = blockIdx.x;
    const int c = threadIdx.x;
    float a = 0.f, d = 0.f;
    #pragma unroll
    for (int s = 0; s < NSPLIT; ++s) {
        a += pacc[((size_t)(s * NN + n)) * NC + c];
        d += pden[(s * NN + n) * 4 + (c >> 6)];
    }
    const float o = d > 0.f ? a / d : 0.f;
    out[(size_t)n * NC + c] = o > 0.f ? o : 0.f;
}

// ---------------------------------------------------------------------------
extern "C" void kernel_launch(void* const* d_in, const int* in_sizes, int n_in,
                              void* d_out, int out_size, void* d_ws, size_t ws_size,
                              hipStream_t stream)
{
    const int*   adj   = (const int*)d_in[0];
    const float* feats = (const float*)d_in[1];
    const float* W     = (const float*)d_in[2];
    const float* ak    = (const float*)d_in[3];

    float* ws     = (float*)d_ws;
    float* hfeat  = ws;                        // 4096*256       = 1,048,576 f
    float* aself  = hfeat + 1048576;           // 16384 f
    float* aneigh = aself + 16384;             // 16384 f
    float* pacc   = aneigh + 16384;            // 4*4096*256     = 4,194,304 f
    float* pden   = pacc + 4194304;            // 4*4096*4       = 65,536 f
    float* out    = (float*)d_out;

    prep_kernel<<<dim3(128, 4), 256, 0, stream>>>(feats, W, ak, hfeat, aself, aneigh);
    attn_kernel<<<dim3(128, NSPLIT), 256, 0, stream>>>(adj, hfeat, aself, aneigh, pacc, pden);
    finalize_kernel<<<NN, 256, 0, stream>>>(pacc, pden, out);
}

// Round 2
// 93.893 us; speedup vs baseline: 3.5799x; 3.5799x over previous
//
#include <hip/hip_runtime.h>
#include <math.h>

#define NN 4096
#define FF 128
#define DD 64
#define HH 4
#define NC 256  // HH*DD output columns

typedef __bf16 bf16x8 __attribute__((ext_vector_type(8)));
typedef float  f32x4  __attribute__((ext_vector_type(4)));

// ---------------------------------------------------------------------------
// Kernel 0: adjacency int32 -> bitmask. adjw[n*128 + w] bit b = (adj[n][w*32+b] != 0)
// Coalesced read of the 64 MB adj exactly once.
// ---------------------------------------------------------------------------
__global__ __launch_bounds__(256) void adjbits_kernel(
    const int* __restrict__ adj, unsigned int* __restrict__ adjw)
{
    const int row  = blockIdx.x;
    const int wv   = threadIdx.x >> 6;
    const int lane = threadIdx.x & 63;
    for (int c = wv; c < 64; c += 4) {
        int a = adj[(size_t)row * NN + c * 64 + lane];
        unsigned long long m = __ballot(a != 0);
        if (lane == 0) {
            adjw[row * 128 + c * 2]     = (unsigned int)m;
            adjw[row * 128 + c * 2 + 1] = (unsigned int)(m >> 32);
        }
    }
}

// ---------------------------------------------------------------------------
// Kernel 1: h = features @ W[h]; emit Ht (bf16, [h][d][m] transposed) and
// aself/aneigh (fp32, [h][n]).
// ---------------------------------------------------------------------------
__global__ __launch_bounds__(256) void prep_kernel(
    const float* __restrict__ feats, const float* __restrict__ W,
    const float* __restrict__ ak, __bf16* __restrict__ Ht,
    float* __restrict__ aself, float* __restrict__ aneigh)
{
    __shared__ float Wt[64 * 132];   // W[h] transposed [d][f], padded
    __shared__ float ft[32 * 128];   // features tile [r][f]
    const int t  = threadIdx.x;
    const int h  = blockIdx.y;
    const int n0 = blockIdx.x * 32;

    {
        const float* Wh = W + h * (FF * DD);
        #pragma unroll
        for (int j = 0; j < 8; ++j) {
            int idx = j * 256 + t;
            int f   = idx >> 4;
            int d4  = idx & 15;
            float4 v = ((const float4*)Wh)[idx];
            Wt[(d4 * 4 + 0) * 132 + f] = v.x;
            Wt[(d4 * 4 + 1) * 132 + f] = v.y;
            Wt[(d4 * 4 + 2) * 132 + f] = v.z;
            Wt[(d4 * 4 + 3) * 132 + f] = v.w;
        }
        #pragma unroll
        for (int j = 0; j < 4; ++j) {
            int idx = j * 256 + t;
            int r = idx >> 5, f4 = idx & 31;
            ((float4*)ft)[r * 32 + f4] = ((const float4*)feats)[(size_t)(n0 + r) * 32 + f4];
        }
    }
    __syncthreads();

    const int d   = t & 63;
    const int wid = t >> 6;
    float acc[8];
    #pragma unroll
    for (int j = 0; j < 8; ++j) acc[j] = 0.f;

    for (int f4 = 0; f4 < 32; ++f4) {
        const float4 w4 = *(const float4*)&Wt[d * 132 + f4 * 4];
        #pragma unroll
        for (int j = 0; j < 8; ++j) {
            const int r = wid + 4 * j;
            const float4 fv = *(const float4*)&ft[r * 128 + f4 * 4];
            acc[j] += fv.x * w4.x + fv.y * w4.y + fv.z * w4.z + fv.w * w4.w;
        }
    }

    const float aks = ak[h * 128 + d];
    const float akn = ak[h * 128 + 64 + d];
    #pragma unroll
    for (int j = 0; j < 8; ++j) {
        const int r = wid + 4 * j;
        const float hv = acc[j];
        Ht[(size_t)(h * 64 + d) * NN + (n0 + r)] = (__bf16)hv;
        float v1 = hv * aks;
        float v2 = hv * akn;
        #pragma unroll
        for (int m = 32; m >= 1; m >>= 1) {
            v1 += __shfl_xor(v1, m, 64);
            v2 += __shfl_xor(v2, m, 64);
        }
        if (d == 0) {
            aself [h * NN + n0 + r] = v1;
            aneigh[h * NN + n0 + r] = v2;
        }
    }
}

// ---------------------------------------------------------------------------
// Kernel 2: MFMA attention accumulation. No LDS, no barriers.
// Block = 256 thr = 4 waves; wave = head. Rows n0..n0+31, K-split over m.
// A-frag (P) generated in registers; B-frag = 16B load from Ht (L2-resident).
// mfma_f32_16x16x32_bf16: A row = lane&15, k = (lane>>4)*8+j (A and B share
// the (kg,slot)->k map so any within-lane permutation cancels);
// C: col = lane&15, row = (lane>>4)*4 + reg  [verified layout].
// ---------------------------------------------------------------------------
__global__ __launch_bounds__(256, 4) void attn_kernel(
    const unsigned int* __restrict__ adjw, const __bf16* __restrict__ Ht,
    const float* __restrict__ aself, const float* __restrict__ aneigh,
    float* __restrict__ pacc, float* __restrict__ pden, int ksplit)
{
    const int t  = threadIdx.x;
    const int h  = t >> 6;
    const int l  = t & 63;
    const int lr = l & 15;
    const int kg = l >> 4;
    const int n0 = blockIdx.x * 32;
    const int s  = blockIdx.y;

    const float as0 = aself[h * NN + n0 + lr];
    const float as1 = aself[h * NN + n0 + 16 + lr];
    const float* __restrict__ anb  = aneigh + h * NN;
    const __bf16* __restrict__ htb = Ht + (size_t)(h * 64) * NN;

    f32x4 acc[2][4] = {};
    f32x4 dacc[2]   = {};
    bf16x8 ones;
    #pragma unroll
    for (int j = 0; j < 8; ++j) ones[j] = (__bf16)1.0f;

    const int nchunk = ksplit >> 5;
    const int mstart = s * ksplit;
    for (int c = 0; c < nchunk; ++c) {
        const int m0 = mstart + c * 32;
        const int mb = m0 + kg * 8;

        const float4 an0 = *(const float4*)(anb + mb);
        const float4 an1 = *(const float4*)(anb + mb + 4);
        const float anv[8] = {an0.x, an0.y, an0.z, an0.w, an1.x, an1.y, an1.z, an1.w};
        const unsigned int w0 = adjw[(n0 + lr) * 128 + (m0 >> 5)];
        const unsigned int w1 = adjw[(n0 + 16 + lr) * 128 + (m0 >> 5)];
        const unsigned int b0 = (w0 >> (kg * 8)) & 0xffu;
        const unsigned int b1 = (w1 >> (kg * 8)) & 0xffu;

        bf16x8 a0, a1;
        #pragma unroll
        for (int j = 0; j < 8; ++j) {
            float s0 = as0 + anv[j];
            float s1 = as1 + anv[j];
            float e0 = __expf(fmaxf(s0, 0.2f * s0));   // exp(leaky_relu(s))
            float e1 = __expf(fmaxf(s1, 0.2f * s1));
            a0[j] = (__bf16)(((b0 >> j) & 1u) ? e0 : 0.0f);
            a1[j] = (__bf16)(((b1 >> j) & 1u) ? e1 : 0.0f);
        }

        bf16x8 bf[4];
        #pragma unroll
        for (int cb = 0; cb < 4; ++cb)
            bf[cb] = *(const bf16x8*)(htb + (size_t)(cb * 16 + lr) * NN + mb);

        #pragma unroll
        for (int cb = 0; cb < 4; ++cb) {
            acc[0][cb] = __builtin_amdgcn_mfma_f32_16x16x32_bf16(a0, bf[cb], acc[0][cb], 0, 0, 0);
            acc[1][cb] = __builtin_amdgcn_mfma_f32_16x16x32_bf16(a1, bf[cb], acc[1][cb], 0, 0, 0);
        }
        dacc[0] = __builtin_amdgcn_mfma_f32_16x16x32_bf16(a0, ones, dacc[0], 0, 0, 0);
        dacc[1] = __builtin_amdgcn_mfma_f32_16x16x32_bf16(a1, ones, dacc[1], 0, 0, 0);
    }

    #pragma unroll
    for (int rb = 0; rb < 2; ++rb) {
        #pragma unroll
        for (int r = 0; r < 4; ++r) {
            const int row = n0 + rb * 16 + kg * 4 + r;
            #pragma unroll
            for (int cb = 0; cb < 4; ++cb)
                pacc[((size_t)(s * NN + row)) * NC + h * 64 + cb * 16 + lr] = acc[rb][cb][r];
            if (lr == 0)
                pden[(s * NN + row) * 4 + h] = dacc[rb][r];
        }
    }
}

// ---------------------------------------------------------------------------
// Kernel 3: reduce splits, normalize, ReLU.
// ---------------------------------------------------------------------------
__global__ __launch_bounds__(256) void finalize_kernel(
    const float* __restrict__ pacc, const float* __restrict__ pden,
    float* __restrict__ out, int nsplit)
{
    const int n = blockIdx.x;
    const int c = threadIdx.x;
    float a = 0.f, d = 0.f;
    for (int s = 0; s < nsplit; ++s) {
        a += pacc[((size_t)(s * NN + n)) * NC + c];
        d += pden[(s * NN + n) * 4 + (c >> 6)];
    }
    const float o = (d > 0.f) ? a / d : 0.f;
    out[(size_t)n * NC + c] = o > 0.f ? o : 0.f;
}

// ---------------------------------------------------------------------------
extern "C" void kernel_launch(void* const* d_in, const int* in_sizes, int n_in,
                              void* d_out, int out_size, void* d_ws, size_t ws_size,
                              hipStream_t stream)
{
    const int*   adj   = (const int*)d_in[0];
    const float* feats = (const float*)d_in[1];
    const float* W     = (const float*)d_in[2];
    const float* ak    = (const float*)d_in[3];
    float*       out   = (float*)d_out;

    char* ws = (char*)d_ws;
    unsigned int* adjw   = (unsigned int*)ws;                       // 2 MB
    __bf16*       Ht     = (__bf16*)(ws + (2ull << 20));            // 2 MB
    float*        aself  = (float*)(ws + (4ull << 20));             // 64 KB
    float*        aneigh = (float*)(ws + (4ull << 20) + (1 << 16)); // 64 KB
    float*        pden   = (float*)(ws + (4ull << 20) + (2 << 16)); // <=512 KB
    float*        pacc   = (float*)(ws + (5ull << 20));             // nsplit*4 MB

    int nsplit = 8;
    while (nsplit > 1 && ws_size < (5ull << 20) + (size_t)nsplit * (4ull << 20))
        nsplit >>= 1;
    const int ksplit = NN / nsplit;

    adjbits_kernel<<<NN, 256, 0, stream>>>(adj, adjw);
    prep_kernel<<<dim3(128, 4), 256, 0, stream>>>(feats, W, ak, Ht, aself, aneigh);
    attn_kernel<<<dim3(128, nsplit), 256, 0, stream>>>(adjw, Ht, aself, aneigh, pacc, pden, ksplit);
    finalize_kernel<<<NN, 256, 0, stream>>>(pacc, pden, out, nsplit);
}